// Round 4
// baseline (530.099 us; speedup 1.0000x reference)
//
#include <hip/hip_runtime.h>
#include <hip/hip_bf16.h>
#include <cstdint>
#include <cstddef>

// B=4, L=8192, D=1024, N=16 selective SSM.
// Phase 1: x -> bf16 (16B stores); Wd/Wb/Wc packed -> bf16 [1152,1024]
// Phase 2: bf16 MFMA GEMM [32768,1024]x[1024,1152]: cols 0-1023 -> softplus -> delta,
//          written TRANSPOSED as deltaT[b][d][l] via LDS-staged tile (coalesced 16B
//          stores in 256B runs); 1024-1039 -> Bm(f32), 1040-1055 -> Cm(f32).
// Phase 3: chunked scan (CHUNKS=16, warm 128), n-split x4 (lane quad per d, 4 n/lane,
//          packed f32x2), ping-pong prefetch PINNED with sched_barrier(0):
//          r3 evidence: compiler collapsed the source-level ping-pong (VGPR=40 < the
//          ~80 two live sets need) and re-sank loads -> VALUBusy stuck 61%, ~40%
//          vmcnt-stall bubble. sched_barrier(0) fences forbid the sink; next-body
//          loads stay in flight across current-body compute (~300 issue cycles).
//          h +-100 clamp dropped (never fires: stationary |h| <~ 10, >13 sigma).

#define LOG2E 1.44269504088896340736f

typedef short bf16x8 __attribute__((ext_vector_type(8)));
typedef unsigned short u16x8 __attribute__((ext_vector_type(8)));
typedef float f32x4 __attribute__((ext_vector_type(4)));
typedef float f32x2 __attribute__((ext_vector_type(2)));

#define SB() __builtin_amdgcn_sched_barrier(0)

// Guaranteed-native exponential: builtin exp2 when available (arg pre-scaled by
// log2e); otherwise __expf == native v_mul_f32 + v_exp_f32.
#if __has_builtin(__builtin_amdgcn_exp2f)
#define EXPA(x) __builtin_amdgcn_exp2f(x)
#define A_SCALE LOG2E
#else
#define EXPA(x) __expf(x)
#define A_SCALE 1.0f
#endif

static __device__ __forceinline__ f32x2 pk_fma2(f32x2 a, f32x2 b, f32x2 c) {
#if __has_builtin(__builtin_elementwise_fma)
    return __builtin_elementwise_fma(a, b, c);
#else
    f32x2 r;
    r.x = fmaf(a.x, b.x, c.x);
    r.y = fmaf(a.y, b.y, c.y);
    return r;
#endif
}

static __device__ __forceinline__ float qsum(float yl) {
    // butterfly sum over the 4 lanes of a quad (all lanes end with the sum)
    yl += __int_as_float(__builtin_amdgcn_update_dpp(
        0, __float_as_int(yl), 0xB1, 0xF, 0xF, true));  // quad_perm(1,0,3,2)
    yl += __int_as_float(__builtin_amdgcn_update_dpp(
        0, __float_as_int(yl), 0x4E, 0xF, 0xF, true));  // quad_perm(2,3,0,1)
    return yl;
}

static constexpr int B_ = 4;
static constexpr int L_ = 8192;
static constexpr int CHUNKS = 16;
static constexpr int CHUNK = L_ / CHUNKS; // 512
static constexpr int WARM = 128;

// ---------------- conversion kernels ----------------

__global__ void cvt_x_kernel(const float* __restrict__ x, unsigned short* __restrict__ xb) {
    size_t i = ((size_t)blockIdx.x * blockDim.x + threadIdx.x) * 8;
    float4 a = *(const float4*)(x + i);
    float4 b = *(const float4*)(x + i + 4);
    u16x8 o;
    float f[8] = {a.x, a.y, a.z, a.w, b.x, b.y, b.z, b.w};
#pragma unroll
    for (int k = 0; k < 8; ++k) {
        __hip_bfloat16 h = __float2bfloat16(f[k]);
        o[k] = *(unsigned short*)&h;
    }
    *(u16x8*)(xb + i) = o;   // one 16B store
}

__global__ void prep_wall_kernel(const float* __restrict__ Wd, const float* __restrict__ Wb,
                                 const float* __restrict__ Wc, __hip_bfloat16* __restrict__ Wall) {
    int gid = blockIdx.x * blockDim.x + threadIdx.x;
    size_t idx = (size_t)gid * 4;
    int row = (int)(idx >> 10);
    int k = (int)(idx & 1023);
    __hip_bfloat16* p = Wall + idx;
    const float* src = nullptr;
    if (row < 1024) src = Wd + (size_t)row * 1024 + k;
    else if (row < 1040) src = Wb + (size_t)(row - 1024) * 1024 + k;
    else if (row < 1056) src = Wc + (size_t)(row - 1040) * 1024 + k;
    if (src) {
        float4 v = *(const float4*)src;
        p[0] = __float2bfloat16(v.x);
        p[1] = __float2bfloat16(v.y);
        p[2] = __float2bfloat16(v.z);
        p[3] = __float2bfloat16(v.w);
    } else {
        __hip_bfloat16 z = __float2bfloat16(0.0f);
        p[0] = z; p[1] = z; p[2] = z; p[3] = z;
    }
}

// ---------------- fused projection GEMM ----------------
// 128x128 tile, 4 waves (2x2), 64x64/wave, 16x16x32 bf16 MFMA, BK=64,
// XOR-swizzled LDS (16B granules): global_load_lds lane-linear, frag reads <=2-way.
// Epilogue (bn<8): fast softplus, bf16 tile staged in LDS as [d][l] (stride 136
// shorts: rows 16B-aligned, <=4-way bank aliasing), then 16B stores to deltaT in
// 256B contiguous runs (r3's direct scatter-store cost ~23us; this re-coalesces).

__global__ __launch_bounds__(256) void gemm_kernel(
    const __hip_bfloat16* __restrict__ X, const __hip_bfloat16* __restrict__ W,
    const float* __restrict__ bd, const float* __restrict__ bb, const float* __restrict__ bc,
    __hip_bfloat16* __restrict__ deltaT, float* __restrict__ Bm, float* __restrict__ Cm) {
    __shared__ short smem[128 * 136];  // 34,816B; K-loop uses first 32KB as As|Bs
    short* As = smem;
    short* Bs = smem + 128 * 64;
    const int bm = blockIdx.x;
    const int bn = blockIdx.y;
    const int t = threadIdx.x;
    const int lane = t & 63;
    const int wave = t >> 6;
    const int wm = (wave >> 1) * 64;
    const int wn = (wave & 1) * 64;
    const int rowS = t >> 3;
    const int kbS = t & 7;

    f32x4 acc[4][4];
#pragma unroll
    for (int i = 0; i < 4; ++i)
#pragma unroll
        for (int j = 0; j < 4; ++j) {
            f32x4 z = {0.f, 0.f, 0.f, 0.f};
            acc[i][j] = z;
        }

    const size_t Abase = (size_t)bm * 128 * 1024;
    const size_t Bbase = (size_t)bn * 128 * 1024;

    for (int kt = 0; kt < 16; ++kt) {
        __syncthreads();
#pragma unroll
        for (int r = 0; r < 4; ++r) {
            int row = r * 32 + rowS;
            int kb = kbS ^ (row & 7);
            const __hip_bfloat16* ga = X + Abase + (size_t)row * 1024 + kt * 64 + kb * 8;
            const __hip_bfloat16* gb = W + Bbase + (size_t)row * 1024 + kt * 64 + kb * 8;
            __builtin_amdgcn_global_load_lds(
                (const __attribute__((address_space(1))) unsigned int*)ga,
                (__attribute__((address_space(3))) unsigned int*)&As[(r * 256 + t) * 8], 16, 0, 0);
            __builtin_amdgcn_global_load_lds(
                (const __attribute__((address_space(1))) unsigned int*)gb,
                (__attribute__((address_space(3))) unsigned int*)&Bs[(r * 256 + t) * 8], 16, 0, 0);
        }
        __syncthreads();
#pragma unroll
        for (int ks = 0; ks < 2; ++ks) {
            bf16x8 af[4], bfr[4];
#pragma unroll
            for (int i = 0; i < 4; ++i) {
                int m = wm + i * 16 + (lane & 15);
                int kb = (ks * 4 + (lane >> 4)) ^ (m & 7);
                af[i] = *(const bf16x8*)&As[m * 64 + kb * 8];
            }
#pragma unroll
            for (int j = 0; j < 4; ++j) {
                int n = wn + j * 16 + (lane & 15);
                int kb = (ks * 4 + (lane >> 4)) ^ (n & 7);
                bfr[j] = *(const bf16x8*)&Bs[n * 64 + kb * 8];
            }
#pragma unroll
            for (int i = 0; i < 4; ++i)
#pragma unroll
                for (int j = 0; j < 4; ++j)
                    acc[i][j] = __builtin_amdgcn_mfma_f32_16x16x32_bf16(af[i], bfr[j], acc[i][j], 0, 0, 0);
        }
    }

    const int rquad = lane >> 4;
    const int cl = lane & 15;
    if (bn < 8) {
        __syncthreads();  // other waves may still read As/Bs
        // stage bf16 delta tile into LDS as [d_local][l_local], stride 136 shorts
#pragma unroll
        for (int j = 0; j < 4; ++j) {
            int dloc = wn + j * 16 + cl;
            float bv = bd[bn * 128 + dloc];
#pragma unroll
            for (int i = 0; i < 4; ++i) {
                int lloc = wm + i * 16 + rquad * 4;
                unsigned short s[4];
#pragma unroll
                for (int r = 0; r < 4; ++r) {
                    float z = acc[i][j][r] + bv;
                    float sp = fmaxf(z, 0.f) + __logf(1.f + __expf(-fabsf(z)));
                    __hip_bfloat16 hb = __float2bfloat16(sp);
                    s[r] = *(unsigned short*)&hb;
                }
                uint2 pk;
                pk.x = (uint32_t)s[0] | ((uint32_t)s[1] << 16);
                pk.y = (uint32_t)s[2] | ((uint32_t)s[3] << 16);
                *(uint2*)&smem[dloc * 136 + lloc] = pk;
            }
        }
        __syncthreads();
        // coalesced write-out: 16 lanes cover one d-row's 256B of l
        const int bidx = bm >> 6;          // batch
        const int l0g = (bm & 63) * 128;   // l offset within batch
        const int rloc = t >> 4;
        const int seg = t & 15;
#pragma unroll
        for (int p = 0; p < 8; ++p) {
            int dl_ = p * 16 + rloc;
            bf16x8 v = *(const bf16x8*)&smem[dl_ * 136 + seg * 8];
            *(bf16x8*)(deltaT + ((size_t)bidx * 1024 + bn * 128 + dl_) * 8192 + l0g + seg * 8) = v;
        }
    } else {
#pragma unroll
        for (int i = 0; i < 4; ++i) {
            int mrow = bm * 128 + wm + i * 16 + rquad * 4;
#pragma unroll
            for (int j = 0; j < 4; ++j) {
                int cloc = wn + j * 16 + cl;
                if (cloc < 16) {
                    float bv = bb[cloc];
#pragma unroll
                    for (int r = 0; r < 4; ++r)
                        Bm[(size_t)(mrow + r) * 16 + cloc] = acc[i][j][r] + bv;
                } else if (cloc < 32) {
                    float bv = bc[cloc - 16];
#pragma unroll
                    for (int r = 0; r < 4; ++r)
                        Cm[(size_t)(mrow + r) * 16 + (cloc - 16)] = acc[i][j][r] + bv;
                }
            }
        }
    }
}

// ---------------- chunked sequential scan (pinned ping-pong prefetch) ----------------
// 1024 blocks x 256 threads: (b:4, chunk:16, dblk:16 of 64 d); lane quad owns one d,
// each lane 4 n-states (2x f32x2). Two full register sets (delta-pack, x, B[4], C[4])
// alternate; sched_barrier(0) fences pin next-body loads BEFORE current-body compute
// so they stay in flight ~1 body (~300 issue cycles), covering L2 latency.
// delta from deltaT[b][d][l]: one 8B load/body (quad-uniform). y: per-lane step
// select (nq==u), one store/body. No h clamp (never active). B-clip via v_med3.

__global__ __launch_bounds__(256, 4) void scan_kernel(
    const __hip_bfloat16* __restrict__ deltaT, const __hip_bfloat16* __restrict__ xb,
    const float* __restrict__ Bmg, const float* __restrict__ Cmg,
    const float* __restrict__ A_log, const float* __restrict__ Dparam,
    float* __restrict__ y) {
    const int bid = blockIdx.x;
    const int dblk = bid & 15;          // 16 blocks of 64 d
    const int c = (bid >> 4) & 15;      // 16 chunks
    const int b = bid >> 8;
    const int t = threadIdx.x;
    const int nq = t & 3;               // lane's n-quad within its d
    const int d = dblk * 64 + (t >> 2);
    const int n0 = nq * 4;

    f32x2 A2p[2];
#pragma unroll
    for (int q = 0; q < 2; ++q) {
        A2p[q].x = -__expf(A_log[d * 16 + n0 + 2 * q]) * A_SCALE;  // A<0 (pre-scaled)
        A2p[q].y = -__expf(A_log[d * 16 + n0 + 2 * q + 1]) * A_SCALE;
    }
    const float Dp = Dparam[d];

    f32x2 h0 = {0.f, 0.f};
    f32x2 h1 = {0.f, 0.f};

    const int lmain = c * CHUNK;
    const int warm = (c == 0) ? 0 : WARM;
    const int l0 = lmain - warm;
    const size_t baseBL = (size_t)b * L_;

    const __hip_bfloat16* dptr = deltaT + ((size_t)b * 1024 + d) * 8192 + l0;
    const __hip_bfloat16* xptr = xb + (baseBL + l0) * 1024 + d;
    const float* bcp = Bmg + (baseBL + l0) * 16 + n0;
    const float* ccp = Cmg + (baseBL + lmain) * 16 + n0;
    float* yst = y + (baseBL + lmain) * 1024 + d + (size_t)nq * 1024;

    // register sets A/B (ping-pong)
    uint2 dwA, dwB;
    float xvA[4], xvB[4];
    f32x4 bsA[4], bsB[4], csA[4], csB[4];

#define LOAD_DX(DW, XV) do { \
        DW = *(const uint2*)dptr; dptr += 4; \
        XV[0] = __bfloat162float(xptr[0]); \
        XV[1] = __bfloat162float(xptr[1024]); \
        XV[2] = __bfloat162float(xptr[2048]); \
        XV[3] = __bfloat162float(xptr[3072]); \
        xptr += 4096; } while (0)

#define LOAD_B4(BS) do { \
        BS[0] = *(const f32x4*)(bcp); \
        BS[1] = *(const f32x4*)(bcp + 16); \
        BS[2] = *(const f32x4*)(bcp + 32); \
        BS[3] = *(const f32x4*)(bcp + 48); \
        bcp += 64; } while (0)

#define LOAD_C4(CS) do { \
        CS[0] = *(const f32x4*)(ccp); \
        CS[1] = *(const f32x4*)(ccp + 16); \
        CS[2] = *(const f32x4*)(ccp + 32); \
        CS[3] = *(const f32x4*)(ccp + 48); \
        ccp += 64; } while (0)

#define STEP_H(DLT, XU, BSU) do { \
        const f32x2 dlt2 = {(DLT), (DLT)}; \
        f32x2 tA0 = dlt2 * A2p[0]; \
        f32x2 tA1 = dlt2 * A2p[1]; \
        f32x2 a0 = {EXPA(tA0.x), EXPA(tA0.y)}; \
        f32x2 a1 = {EXPA(tA1.x), EXPA(tA1.y)}; \
        f32x2 blo = {(BSU)[0], (BSU)[1]}; \
        f32x2 bhi = {(BSU)[2], (BSU)[3]}; \
        f32x2 tB0 = dlt2 * blo; \
        f32x2 tB1 = dlt2 * bhi; \
        tB0.x = __builtin_amdgcn_fmed3f(tB0.x, -2.f, 2.f); \
        tB0.y = __builtin_amdgcn_fmed3f(tB0.y, -2.f, 2.f); \
        tB1.x = __builtin_amdgcn_fmed3f(tB1.x, -2.f, 2.f); \
        tB1.y = __builtin_amdgcn_fmed3f(tB1.y, -2.f, 2.f); \
        const f32x2 xu2 = {(XU), (XU)}; \
        h0 = pk_fma2(a0, h0, tB0 * xu2); \
        h1 = pk_fma2(a1, h1, tB1 * xu2); } while (0)

#define WARM_BODY(DW, XV, BS) do { \
        float _dl[4] = {__int_as_float(DW.x << 16), __int_as_float(DW.x & 0xffff0000u), \
                        __int_as_float(DW.y << 16), __int_as_float(DW.y & 0xffff0000u)}; \
        _Pragma("unroll") \
        for (int u = 0; u < 4; ++u) STEP_H(_dl[u], XV[u], BS[u]); } while (0)

#define MAIN_BODY(DW, XV, BS, CS) do { \
        float _dl[4] = {__int_as_float(DW.x << 16), __int_as_float(DW.x & 0xffff0000u), \
                        __int_as_float(DW.y << 16), __int_as_float(DW.y & 0xffff0000u)}; \
        float _yk = 0.f; \
        _Pragma("unroll") \
        for (int u = 0; u < 4; ++u) { \
            STEP_H(_dl[u], XV[u], BS[u]); \
            f32x2 clo = {(CS)[u][0], (CS)[u][1]}; \
            f32x2 chi = {(CS)[u][2], (CS)[u][3]}; \
            f32x2 y2 = pk_fma2(h1, chi, h0 * clo); \
            float yv = fmaf(XV[u], Dp, qsum(y2.x + y2.y)); \
            if (nq == u) _yk = yv; \
        } \
        *yst = _yk; yst += 4096; } while (0)

    // prologue: body 0 (of warmup, or of main when c==0) into set A
    LOAD_B4(bsA);
    LOAD_DX(dwA, xvA);

    // -------- warmup: evolve h only (no C, no y) --------
    if (c != 0) {
#pragma unroll 1
        for (int bo = 0; bo < (WARM >> 2); bo += 2) {
            LOAD_B4(bsB);
            LOAD_DX(dwB, xvB);
            SB();
            WARM_BODY(dwA, xvA, bsA);
            SB();
            LOAD_B4(bsA);
            LOAD_DX(dwA, xvA);
            SB();
            WARM_BODY(dwB, xvB, bsB);
            SB();
        }
        // set A now holds main body 0; streams point at main body 1
    }

    // -------- main: full recurrence + y emit --------
    LOAD_C4(csA);  // C for main body 0
#pragma unroll 1
    for (int bo = 0; bo < (CHUNK >> 2); bo += 2) {
        LOAD_B4(bsB);
        LOAD_C4(csB);
        LOAD_DX(dwB, xvB);
        SB();
        MAIN_BODY(dwA, xvA, bsA, csA);
        SB();
        LOAD_B4(bsA);
        LOAD_C4(csA);
        LOAD_DX(dwA, xvA);      // final iter over-reads one body: lands in-ws (layout)
        SB();
        MAIN_BODY(dwB, xvB, bsB, csB);
        SB();
    }

#undef LOAD_DX
#undef LOAD_B4
#undef LOAD_C4
#undef STEP_H
#undef WARM_BODY
#undef MAIN_BODY
}

// ---------------- launch ----------------

extern "C" void kernel_launch(void* const* d_in, const int* in_sizes, int n_in,
                              void* d_out, int out_size, void* d_ws, size_t ws_size,
                              hipStream_t stream) {
    const float* x      = (const float*)d_in[0];
    const float* Wd     = (const float*)d_in[1];
    const float* bd     = (const float*)d_in[2];
    const float* Wb     = (const float*)d_in[3];
    const float* bb     = (const float*)d_in[4];
    const float* Wc     = (const float*)d_in[5];
    const float* bc     = (const float*)d_in[6];
    const float* A_log  = (const float*)d_in[7];
    const float* Dparam = (const float*)d_in[8];
    float* y = (float*)d_out;

    // ws layout ordered so scan prefetch over-reads land in the next region:
    // Bm -> Cm -> xb -> deltaT -> Wall (Wall never over-read). Total 140,771,328 B.
    char* ws = (char*)d_ws;
    float* Bm              = (float*)(ws);                          //  2,097,152
    float* Cm              = (float*)(ws + 2097152);                //  2,097,152
    __hip_bfloat16* xb     = (__hip_bfloat16*)(ws + 4194304);       // 67,108,864
    __hip_bfloat16* deltaT = (__hip_bfloat16*)(ws + 71303168);      // 67,108,864
    __hip_bfloat16* Wall   = (__hip_bfloat16*)(ws + 138412032);     //  2,359,296

    cvt_x_kernel<<<16384, 256, 0, stream>>>(x, (unsigned short*)xb);
    prep_wall_kernel<<<1152, 256, 0, stream>>>(Wd, Wb, Wc, Wall);
    gemm_kernel<<<dim3(256, 9), 256, 0, stream>>>(xb, Wall, bd, bb, bc, deltaT, Bm, Cm);
    scan_kernel<<<1024, 256, 0, stream>>>(deltaT, xb, Bm, Cm, A_log, Dparam, y);
}

// Round 6
// 518.869 us; speedup vs baseline: 1.0216x; 1.0216x over previous
//
#include <hip/hip_runtime.h>
#include <hip/hip_bf16.h>
#include <cstdint>
#include <cstddef>

// B=4, L=8192, D=1024, N=16 selective SSM.
// Phase 1: x -> bf16 (16B stores); Wd/Wb/Wc packed -> bf16 [1152,1024]
// Phase 2: bf16 MFMA GEMM [32768,1024]x[1024,1152] with XCD-grouped tile swizzle
//          (2304 blocks = 8 xcd x 32 bm x 9 bn: the 9 bn-tiles of one bm run
//          consecutively on ONE XCD -> X tile fetched once per L2, not 9x from HBM).
//          cols 0-1023 -> softplus -> delta, written TRANSPOSED as deltaT[b][d][l]
//          via LDS-staged tile; 1024-1039 -> Bm(f32), 1040-1055 -> Cm(f32).
// Phase 3: chunked scan (CHUNKS=8, chunk 1024, warm 128), n-split x4 (lane quad per
//          d, 4 n/lane, f32x2 elementwise builtins -- r5's inline-asm v_pk_* was
//          numerically wrong, REVERTED; gfx950 ISel packs v2f32 natively).
//          r0-r4 evidence: scan is VALU-issue-bound (time tracks instruction count;
//          occupancy 20-71% no effect; pinned prefetch no effect), so the lever is
//          fewer steps: CHUNKS=8 cuts warm redundancy to 9088 steps (-10%).
//          h +-100 clamp dropped (never fires: stationary |h| <~ 10, >13 sigma).

#define LOG2E 1.44269504088896340736f

typedef short bf16x8 __attribute__((ext_vector_type(8)));
typedef unsigned short u16x8 __attribute__((ext_vector_type(8)));
typedef float f32x4 __attribute__((ext_vector_type(4)));
typedef float f32x2 __attribute__((ext_vector_type(2)));

#define SB() __builtin_amdgcn_sched_barrier(0)

// Guaranteed-native exponential: builtin exp2 when available (arg pre-scaled by
// log2e); otherwise __expf == native v_mul_f32 + v_exp_f32.
#if __has_builtin(__builtin_amdgcn_exp2f)
#define EXPA(x) __builtin_amdgcn_exp2f(x)
#define A_SCALE LOG2E
#else
#define EXPA(x) __expf(x)
#define A_SCALE 1.0f
#endif

static __device__ __forceinline__ f32x2 pk_fma2(f32x2 a, f32x2 b, f32x2 c) {
#if __has_builtin(__builtin_elementwise_fma)
    return __builtin_elementwise_fma(a, b, c);
#else
    f32x2 r;
    r.x = fmaf(a.x, b.x, c.x);
    r.y = fmaf(a.y, b.y, c.y);
    return r;
#endif
}

static __device__ __forceinline__ float qsum(float yl) {
    // butterfly sum over the 4 lanes of a quad (all lanes end with the sum)
    yl += __int_as_float(__builtin_amdgcn_update_dpp(
        0, __float_as_int(yl), 0xB1, 0xF, 0xF, true));  // quad_perm(1,0,3,2)
    yl += __int_as_float(__builtin_amdgcn_update_dpp(
        0, __float_as_int(yl), 0x4E, 0xF, 0xF, true));  // quad_perm(2,3,0,1)
    return yl;
}

static constexpr int B_ = 4;
static constexpr int L_ = 8192;
static constexpr int CHUNKS = 8;
static constexpr int CHUNK = L_ / CHUNKS; // 1024
static constexpr int WARM = 128;

// ---------------- conversion kernels ----------------

__global__ void cvt_x_kernel(const float* __restrict__ x, unsigned short* __restrict__ xb) {
    size_t i = ((size_t)blockIdx.x * blockDim.x + threadIdx.x) * 8;
    float4 a = *(const float4*)(x + i);
    float4 b = *(const float4*)(x + i + 4);
    u16x8 o;
    float f[8] = {a.x, a.y, a.z, a.w, b.x, b.y, b.z, b.w};
#pragma unroll
    for (int k = 0; k < 8; ++k) {
        __hip_bfloat16 h = __float2bfloat16(f[k]);
        o[k] = *(unsigned short*)&h;
    }
    *(u16x8*)(xb + i) = o;   // one 16B store
}

__global__ void prep_wall_kernel(const float* __restrict__ Wd, const float* __restrict__ Wb,
                                 const float* __restrict__ Wc, __hip_bfloat16* __restrict__ Wall) {
    int gid = blockIdx.x * blockDim.x + threadIdx.x;
    size_t idx = (size_t)gid * 4;
    int row = (int)(idx >> 10);
    int k = (int)(idx & 1023);
    __hip_bfloat16* p = Wall + idx;
    const float* src = nullptr;
    if (row < 1024) src = Wd + (size_t)row * 1024 + k;
    else if (row < 1040) src = Wb + (size_t)(row - 1024) * 1024 + k;
    else if (row < 1056) src = Wc + (size_t)(row - 1040) * 1024 + k;
    if (src) {
        float4 v = *(const float4*)src;
        p[0] = __float2bfloat16(v.x);
        p[1] = __float2bfloat16(v.y);
        p[2] = __float2bfloat16(v.z);
        p[3] = __float2bfloat16(v.w);
    } else {
        __hip_bfloat16 z = __float2bfloat16(0.0f);
        p[0] = z; p[1] = z; p[2] = z; p[3] = z;
    }
}

// ---------------- fused projection GEMM ----------------
// 128x128 tile, 4 waves (2x2), 64x64/wave, 16x16x32 bf16 MFMA, BK=64,
// XOR-swizzled LDS (16B granules): global_load_lds lane-linear, frag reads <=2-way.
// Tile swizzle: linear block id L -> xcd=L&7 (dispatch round-robin), bm=xcd*32+(L>>3)/9,
// bn=(L>>3)%9. Bijective (2304=8*32*9). Same-bm blocks are temporally adjacent on one
// XCD -> X tile (256KB) HBM-fetched once, L2-served 8x (was 9x HBM = ~516MB extra).
// Epilogue (bn<8): fast softplus, bf16 tile staged in LDS as [d][l] (stride 136),
// then 16B stores to deltaT in 256B contiguous runs.

__global__ __launch_bounds__(256) void gemm_kernel(
    const __hip_bfloat16* __restrict__ X, const __hip_bfloat16* __restrict__ W,
    const float* __restrict__ bd, const float* __restrict__ bb, const float* __restrict__ bc,
    __hip_bfloat16* __restrict__ deltaT, float* __restrict__ Bm, float* __restrict__ Cm) {
    __shared__ short smem[128 * 136];  // 34,816B; K-loop uses first 32KB as As|Bs
    short* As = smem;
    short* Bs = smem + 128 * 64;
    const int Lid = blockIdx.x + (blockIdx.y << 8);  // 0..2303
    const int xcd = Lid & 7;
    const int idx = Lid >> 3;                        // 0..287
    const int bm = xcd * 32 + idx / 9;
    const int bn = idx % 9;
    const int t = threadIdx.x;
    const int lane = t & 63;
    const int wave = t >> 6;
    const int wm = (wave >> 1) * 64;
    const int wn = (wave & 1) * 64;
    const int rowS = t >> 3;
    const int kbS = t & 7;

    f32x4 acc[4][4];
#pragma unroll
    for (int i = 0; i < 4; ++i)
#pragma unroll
        for (int j = 0; j < 4; ++j) {
            f32x4 z = {0.f, 0.f, 0.f, 0.f};
            acc[i][j] = z;
        }

    const size_t Abase = (size_t)bm * 128 * 1024;
    const size_t Bbase = (size_t)bn * 128 * 1024;

    for (int kt = 0; kt < 16; ++kt) {
        __syncthreads();
#pragma unroll
        for (int r = 0; r < 4; ++r) {
            int row = r * 32 + rowS;
            int kb = kbS ^ (row & 7);
            const __hip_bfloat16* ga = X + Abase + (size_t)row * 1024 + kt * 64 + kb * 8;
            const __hip_bfloat16* gb = W + Bbase + (size_t)row * 1024 + kt * 64 + kb * 8;
            __builtin_amdgcn_global_load_lds(
                (const __attribute__((address_space(1))) unsigned int*)ga,
                (__attribute__((address_space(3))) unsigned int*)&As[(r * 256 + t) * 8], 16, 0, 0);
            __builtin_amdgcn_global_load_lds(
                (const __attribute__((address_space(1))) unsigned int*)gb,
                (__attribute__((address_space(3))) unsigned int*)&Bs[(r * 256 + t) * 8], 16, 0, 0);
        }
        __syncthreads();
#pragma unroll
        for (int ks = 0; ks < 2; ++ks) {
            bf16x8 af[4], bfr[4];
#pragma unroll
            for (int i = 0; i < 4; ++i) {
                int m = wm + i * 16 + (lane & 15);
                int kb = (ks * 4 + (lane >> 4)) ^ (m & 7);
                af[i] = *(const bf16x8*)&As[m * 64 + kb * 8];
            }
#pragma unroll
            for (int j = 0; j < 4; ++j) {
                int n = wn + j * 16 + (lane & 15);
                int kb = (ks * 4 + (lane >> 4)) ^ (n & 7);
                bfr[j] = *(const bf16x8*)&Bs[n * 64 + kb * 8];
            }
#pragma unroll
            for (int i = 0; i < 4; ++i)
#pragma unroll
                for (int j = 0; j < 4; ++j)
                    acc[i][j] = __builtin_amdgcn_mfma_f32_16x16x32_bf16(af[i], bfr[j], acc[i][j], 0, 0, 0);
        }
    }

    const int rquad = lane >> 4;
    const int cl = lane & 15;
    if (bn < 8) {
        __syncthreads();  // other waves may still read As/Bs
        // stage bf16 delta tile into LDS as [d_local][l_local], stride 136 shorts
#pragma unroll
        for (int j = 0; j < 4; ++j) {
            int dloc = wn + j * 16 + cl;
            float bv = bd[bn * 128 + dloc];
#pragma unroll
            for (int i = 0; i < 4; ++i) {
                int lloc = wm + i * 16 + rquad * 4;
                unsigned short s[4];
#pragma unroll
                for (int r = 0; r < 4; ++r) {
                    float z = acc[i][j][r] + bv;
                    float sp = fmaxf(z, 0.f) + __logf(1.f + __expf(-fabsf(z)));
                    __hip_bfloat16 hb = __float2bfloat16(sp);
                    s[r] = *(unsigned short*)&hb;
                }
                uint2 pk;
                pk.x = (uint32_t)s[0] | ((uint32_t)s[1] << 16);
                pk.y = (uint32_t)s[2] | ((uint32_t)s[3] << 16);
                *(uint2*)&smem[dloc * 136 + lloc] = pk;
            }
        }
        __syncthreads();
        // coalesced write-out: 16 lanes cover one d-row's 256B of l
        const int bidx = bm >> 6;          // batch
        const int l0g = (bm & 63) * 128;   // l offset within batch
        const int rloc = t >> 4;
        const int seg = t & 15;
#pragma unroll
        for (int p = 0; p < 8; ++p) {
            int dl_ = p * 16 + rloc;
            bf16x8 v = *(const bf16x8*)&smem[dl_ * 136 + seg * 8];
            *(bf16x8*)(deltaT + ((size_t)bidx * 1024 + bn * 128 + dl_) * 8192 + l0g + seg * 8) = v;
        }
    } else {
#pragma unroll
        for (int i = 0; i < 4; ++i) {
            int mrow = bm * 128 + wm + i * 16 + rquad * 4;
#pragma unroll
            for (int j = 0; j < 4; ++j) {
                int cloc = wn + j * 16 + cl;
                if (cloc < 16) {
                    float bv = bb[cloc];
#pragma unroll
                    for (int r = 0; r < 4; ++r)
                        Bm[(size_t)(mrow + r) * 16 + cloc] = acc[i][j][r] + bv;
                } else if (cloc < 32) {
                    float bv = bc[cloc - 16];
#pragma unroll
                    for (int r = 0; r < 4; ++r)
                        Cm[(size_t)(mrow + r) * 16 + (cloc - 16)] = acc[i][j][r] + bv;
                }
            }
        }
    }
}

// ---------------- chunked sequential scan (ping-pong prefetch) ----------------
// 512 blocks x 256 threads: (b:4, chunk:8, dblk:16 of 64 d); lane quad owns one d,
// each lane 4 n-states (2x f32x2, elementwise builtins -> backend packs v2f32).
// Ping-pong register sets + sched_barrier fences; delta from deltaT[b][d][l]:
// one 8B load/body (quad-uniform). y: per-lane step select (nq==u), one store/body.
// No h clamp (never active). B-clip via v_med3.

__global__ __launch_bounds__(256, 2) void scan_kernel(
    const __hip_bfloat16* __restrict__ deltaT, const __hip_bfloat16* __restrict__ xb,
    const float* __restrict__ Bmg, const float* __restrict__ Cmg,
    const float* __restrict__ A_log, const float* __restrict__ Dparam,
    float* __restrict__ y) {
    const int bid = blockIdx.x;
    const int dblk = bid & 15;          // 16 blocks of 64 d
    const int c = (bid >> 4) & 7;       // 8 chunks
    const int b = bid >> 7;
    const int t = threadIdx.x;
    const int nq = t & 3;               // lane's n-quad within its d
    const int d = dblk * 64 + (t >> 2);
    const int n0 = nq * 4;

    f32x2 A2p[2];
#pragma unroll
    for (int q = 0; q < 2; ++q) {
        A2p[q].x = -__expf(A_log[d * 16 + n0 + 2 * q]) * A_SCALE;  // A<0 (pre-scaled)
        A2p[q].y = -__expf(A_log[d * 16 + n0 + 2 * q + 1]) * A_SCALE;
    }
    const float Dp = Dparam[d];

    f32x2 h0 = {0.f, 0.f};
    f32x2 h1 = {0.f, 0.f};

    const int lmain = c * CHUNK;
    const int warm = (c == 0) ? 0 : WARM;
    const int l0 = lmain - warm;
    const size_t baseBL = (size_t)b * L_;

    const __hip_bfloat16* dptr = deltaT + ((size_t)b * 1024 + d) * 8192 + l0;
    const __hip_bfloat16* xptr = xb + (baseBL + l0) * 1024 + d;
    const float* bcp = Bmg + (baseBL + l0) * 16 + n0;
    const float* ccp = Cmg + (baseBL + lmain) * 16 + n0;
    float* yst = y + (baseBL + lmain) * 1024 + d + (size_t)nq * 1024;

    // register sets A/B (ping-pong)
    uint2 dwA, dwB;
    float xvA[4], xvB[4];
    f32x4 bsA[4], bsB[4], csA[4], csB[4];

#define LOAD_DX(DW, XV) do { \
        DW = *(const uint2*)dptr; dptr += 4; \
        XV[0] = __bfloat162float(xptr[0]); \
        XV[1] = __bfloat162float(xptr[1024]); \
        XV[2] = __bfloat162float(xptr[2048]); \
        XV[3] = __bfloat162float(xptr[3072]); \
        xptr += 4096; } while (0)

#define LOAD_B4(BS) do { \
        BS[0] = *(const f32x4*)(bcp); \
        BS[1] = *(const f32x4*)(bcp + 16); \
        BS[2] = *(const f32x4*)(bcp + 32); \
        BS[3] = *(const f32x4*)(bcp + 48); \
        bcp += 64; } while (0)

#define LOAD_C4(CS) do { \
        CS[0] = *(const f32x4*)(ccp); \
        CS[1] = *(const f32x4*)(ccp + 16); \
        CS[2] = *(const f32x4*)(ccp + 32); \
        CS[3] = *(const f32x4*)(ccp + 48); \
        ccp += 64; } while (0)

#define STEP_H(DLT, XU, BSU) do { \
        const f32x2 dlt2 = {(DLT), (DLT)}; \
        f32x2 tA0 = dlt2 * A2p[0]; \
        f32x2 tA1 = dlt2 * A2p[1]; \
        f32x2 a0 = {EXPA(tA0.x), EXPA(tA0.y)}; \
        f32x2 a1 = {EXPA(tA1.x), EXPA(tA1.y)}; \
        f32x2 blo = {(BSU)[0], (BSU)[1]}; \
        f32x2 bhi = {(BSU)[2], (BSU)[3]}; \
        f32x2 tB0 = dlt2 * blo; \
        f32x2 tB1 = dlt2 * bhi; \
        tB0.x = __builtin_amdgcn_fmed3f(tB0.x, -2.f, 2.f); \
        tB0.y = __builtin_amdgcn_fmed3f(tB0.y, -2.f, 2.f); \
        tB1.x = __builtin_amdgcn_fmed3f(tB1.x, -2.f, 2.f); \
        tB1.y = __builtin_amdgcn_fmed3f(tB1.y, -2.f, 2.f); \
        const f32x2 xu2 = {(XU), (XU)}; \
        h0 = pk_fma2(a0, h0, tB0 * xu2); \
        h1 = pk_fma2(a1, h1, tB1 * xu2); } while (0)

#define WARM_BODY(DW, XV, BS) do { \
        float _dl[4] = {__int_as_float(DW.x << 16), __int_as_float(DW.x & 0xffff0000u), \
                        __int_as_float(DW.y << 16), __int_as_float(DW.y & 0xffff0000u)}; \
        _Pragma("unroll") \
        for (int u = 0; u < 4; ++u) STEP_H(_dl[u], XV[u], BS[u]); } while (0)

#define MAIN_BODY(DW, XV, BS, CS) do { \
        float _dl[4] = {__int_as_float(DW.x << 16), __int_as_float(DW.x & 0xffff0000u), \
                        __int_as_float(DW.y << 16), __int_as_float(DW.y & 0xffff0000u)}; \
        float _yk = 0.f; \
        _Pragma("unroll") \
        for (int u = 0; u < 4; ++u) { \
            STEP_H(_dl[u], XV[u], BS[u]); \
            f32x2 clo = {(CS)[u][0], (CS)[u][1]}; \
            f32x2 chi = {(CS)[u][2], (CS)[u][3]}; \
            f32x2 y2 = pk_fma2(h1, chi, h0 * clo); \
            float yv = fmaf(XV[u], Dp, qsum(y2.x + y2.y)); \
            if (nq == u) _yk = yv; \
        } \
        *yst = _yk; yst += 4096; } while (0)

    // prologue: body 0 (of warmup, or of main when c==0) into set A
    LOAD_B4(bsA);
    LOAD_DX(dwA, xvA);

    // -------- warmup: evolve h only (no C, no y) --------
    if (c != 0) {
#pragma unroll 1
        for (int bo = 0; bo < (WARM >> 2); bo += 2) {
            LOAD_B4(bsB);
            LOAD_DX(dwB, xvB);
            SB();
            WARM_BODY(dwA, xvA, bsA);
            SB();
            LOAD_B4(bsA);
            LOAD_DX(dwA, xvA);
            SB();
            WARM_BODY(dwB, xvB, bsB);
            SB();
        }
        // set A now holds main body 0; streams point at main body 1
    }

    // -------- main: full recurrence + y emit --------
    LOAD_C4(csA);  // C for main body 0
#pragma unroll 1
    for (int bo = 0; bo < (CHUNK >> 2); bo += 2) {
        LOAD_B4(bsB);
        LOAD_C4(csB);
        LOAD_DX(dwB, xvB);
        SB();
        MAIN_BODY(dwA, xvA, bsA, csA);
        SB();
        LOAD_B4(bsA);
        LOAD_C4(csA);
        LOAD_DX(dwA, xvA);      // final iter over-reads one body: lands in-ws (layout)
        SB();
        MAIN_BODY(dwB, xvB, bsB, csB);
        SB();
    }

#undef LOAD_DX
#undef LOAD_B4
#undef LOAD_C4
#undef STEP_H
#undef WARM_BODY
#undef MAIN_BODY
}

// ---------------- launch ----------------

extern "C" void kernel_launch(void* const* d_in, const int* in_sizes, int n_in,
                              void* d_out, int out_size, void* d_ws, size_t ws_size,
                              hipStream_t stream) {
    const float* x      = (const float*)d_in[0];
    const float* Wd     = (const float*)d_in[1];
    const float* bd     = (const float*)d_in[2];
    const float* Wb     = (const float*)d_in[3];
    const float* bb     = (const float*)d_in[4];
    const float* Wc     = (const float*)d_in[5];
    const float* bc     = (const float*)d_in[6];
    const float* A_log  = (const float*)d_in[7];
    const float* Dparam = (const float*)d_in[8];
    float* y = (float*)d_out;

    // ws layout ordered so scan prefetch over-reads land in the next region:
    // Bm -> Cm -> xb -> deltaT -> Wall (Wall never over-read). Total 140,771,328 B.
    char* ws = (char*)d_ws;
    float* Bm              = (float*)(ws);                          //  2,097,152
    float* Cm              = (float*)(ws + 2097152);                //  2,097,152
    __hip_bfloat16* xb     = (__hip_bfloat16*)(ws + 4194304);       // 67,108,864
    __hip_bfloat16* deltaT = (__hip_bfloat16*)(ws + 71303168);      // 67,108,864
    __hip_bfloat16* Wall   = (__hip_bfloat16*)(ws + 138412032);     //  2,359,296

    cvt_x_kernel<<<16384, 256, 0, stream>>>(x, (unsigned short*)xb);
    prep_wall_kernel<<<1152, 256, 0, stream>>>(Wd, Wb, Wc, Wall);
    gemm_kernel<<<dim3(256, 9), 256, 0, stream>>>(xb, Wall, bd, bb, bc, deltaT, Bm, Cm);
    scan_kernel<<<512, 256, 0, stream>>>(deltaT, xb, Bm, Cm, A_log, Dparam, y);
}